// Round 3
// baseline (798.635 us; speedup 1.0000x reference)
//
#include <hip/hip_runtime.h>
#include <math.h>
#include <stdint.h>

typedef unsigned short u16;
typedef __bf16 bf16x8 __attribute__((ext_vector_type(8)));
typedef float f32x4 __attribute__((ext_vector_type(4)));

constexpr int Tq = 2048;
constexpr int D  = 1024;
constexpr int NHc = 16;
constexpr int Bc = 2;
constexpr int Mrows = Bc * Tq;   // 4096

__device__ __forceinline__ float wsum(float v){
#pragma unroll
  for(int o=32;o;o>>=1) v += __shfl_xor(v,o);
  return v;
}
__device__ __forceinline__ u16 f2bf(float f){          // RNE fp32->bf16
  union{ float f; unsigned u; } v; v.f = f;
  unsigned r = v.u + 0x7fffu + ((v.u >> 16) & 1u);
  return (u16)(r >> 16);
}
__device__ __forceinline__ float bf2f(u16 b){
  union{ unsigned u; float f; } v; v.u = ((unsigned)b) << 16;
  return v.f;
}
__device__ __forceinline__ void gl2lds16(const void* g, void* l){
  // async global->LDS, 16B/lane; LDS dst = wave-uniform base + lane*16
  __builtin_amdgcn_global_load_lds(
      (const __attribute__((address_space(1))) unsigned int*)g,
      (__attribute__((address_space(3))) unsigned int*)l, 16, 0, 0);
}

// ---------------- fp32 -> bf16 bulk convert (weights) -----------------------
__global__ __launch_bounds__(256) void cvt_kernel(const float* __restrict__ s,
                                                  u16* __restrict__ d){
  const int i = blockIdx.x*256 + threadIdx.x;
  const float4 v = ((const float4*)s)[i];
  ushort4 o; o.x=f2bf(v.x); o.y=f2bf(v.y); o.z=f2bf(v.z); o.w=f2bf(v.w);
  ((ushort4*)d)[i] = o;
}

// ---------------- LayerNorm: one block per row, bf16 out --------------------
__global__ __launch_bounds__(256) void ln_kernel(const float* __restrict__ x,
    const float* __restrict__ g, const float* __restrict__ b,
    u16* __restrict__ xn){
  const int row = blockIdx.x;
  const int tid = threadIdx.x;
  const float4 v = ((const float4*)(x + (size_t)row*D))[tid];
  float s = v.x+v.y+v.z+v.w;
  float q = v.x*v.x+v.y*v.y+v.z*v.z+v.w*v.w;
  s = wsum(s); q = wsum(q);
  __shared__ float sb[4], qb[4];
  if((tid&63)==0){ sb[tid>>6]=s; qb[tid>>6]=q; }
  __syncthreads();
  const float ts = sb[0]+sb[1]+sb[2]+sb[3];
  const float tq = qb[0]+qb[1]+qb[2]+qb[3];
  const float mu   = ts*(1.0f/D);
  const float var  = tq*(1.0f/D) - mu*mu;
  const float rstd = rsqrtf(var + 1e-5f);
  const float4 gv = ((const float4*)g)[tid];
  const float4 bv = ((const float4*)b)[tid];
  ushort4 o;
  o.x = f2bf((v.x-mu)*rstd*gv.x + bv.x);
  o.y = f2bf((v.y-mu)*rstd*gv.y + bv.y);
  o.z = f2bf((v.z-mu)*rstd*gv.z + bv.z);
  o.w = f2bf((v.w-mu)*rstd*gv.w + bv.w);
  ((ushort4*)(xn + (size_t)row*D))[tid] = o;
}

// ---------------- rotary cos/sin table: (T, 32) float2 ----------------------
__global__ __launch_bounds__(256) void rope_tab_kernel(float2* __restrict__ tab){
  const int idx = blockIdx.x*256 + threadIdx.x;   // T*32 = 65536
  const int t = idx >> 5, fi = idx & 31;
  const float inv = powf(10000.0f, -(float)fi*(1.0f/32.0f));
  const float ang = (float)t * inv;
  tab[idx] = make_float2(cosf(ang), sinf(ang));
}

// ---------------- merged proj-1: [q|k|v] = xn @ Win^T + bin, RoPE fused -----
// A (M,1024) bf16, B (3072,1024) bf16. Grid (24, 32). Output stacked
// (3, Mrows, 1024) bf16; for q/k slices the rotary rotation is applied
// in-register on the fp32 accumulators (pair (hp, hp+32) = (j, j+2)).
__global__ __launch_bounds__(256) void gemm_qkv1(
    const u16* __restrict__ A, const u16* __restrict__ B,
    const float* __restrict__ bias, const float2* __restrict__ tab,
    u16* __restrict__ out){
  __shared__ __align__(16) u16 As[128*32];
  __shared__ __align__(16) u16 Bs[128*32];
  const int tid  = threadIdx.x;
  const int lane = tid & 63, wv = tid >> 6;
  const int wRow = (wv >> 1) * 64, wCol = (wv & 1) * 64;
  const int mBase = blockIdx.y*128, nBase = blockIdx.x*128;
  const int quad = lane >> 4, r16 = lane & 15;
  const int sRow = lane >> 2;
  const int sCol = (lane & 3) * 8;
  const char* smemA = (const char*)As;
  const char* smemB = (const char*)Bs;

  f32x4 acc[4][4];
#pragma unroll
  for(int i=0;i<4;i++)
#pragma unroll
    for(int j=0;j<4;j++) acc[i][j] = (f32x4)(0.f);

  for(int k0=0;k0<D;k0+=32){
#pragma unroll
    for(int rdn=0;rdn<2;rdn++){
      const int row = rdn*64 + wv*16 + sRow;
      gl2lds16(A + (size_t)(mBase + row)*D + k0 + sCol,
               (void*)((char*)As + rdn*4096 + wv*1024));
      gl2lds16(B + (size_t)(nBase + row)*D + k0 + sCol,
               (void*)((char*)Bs + rdn*4096 + wv*1024));
    }
    __syncthreads();
    bf16x8 af[4], bfr[4];
#pragma unroll
    for(int i=0;i<4;i++)
      af[i]  = *(const bf16x8*)(smemA + (wRow + i*16 + r16)*64 + quad*16);
#pragma unroll
    for(int j=0;j<4;j++)
      bfr[j] = *(const bf16x8*)(smemB + (wCol + j*16 + r16)*64 + quad*16);
#pragma unroll
    for(int i=0;i<4;i++)
#pragma unroll
      for(int j=0;j<4;j++)
        acc[i][j] = __builtin_amdgcn_mfma_f32_16x16x32_bf16(af[i], bfr[j], acc[i][j], 0,0,0);
    __syncthreads();
  }

  const int sel  = nBase >> 10;          // 0=q 1=k 2=v (tiles never straddle)
  const int nLoc = nBase & 1023;
  u16* C = out + (size_t)sel*Mrows*D;
  if(sel < 2){
#pragma unroll
    for(int i=0;i<4;i++){
#pragma unroll
      for(int jp=0;jp<2;jp++){
        const int hp  = jp*16 + r16;           // 0..31 within head
        const int col = nLoc + wCol + hp;
        const float bv0 = bias[nBase + wCol + hp];
        const float bv1 = bias[nBase + wCol + hp + 32];
#pragma unroll
        for(int reg=0;reg<4;reg++){
          const int mm = mBase + wRow + i*16 + quad*4 + reg;
          const float2 cs = tab[((mm & (Tq-1))<<5) + hp];
          const float a0 = acc[i][jp][reg]   + bv0;
          const float a1 = acc[i][jp+2][reg] + bv1;
          C[(size_t)mm*D + col]      = f2bf(a0*cs.x - a1*cs.y);
          C[(size_t)mm*D + col + 32] = f2bf(a1*cs.x + a0*cs.y);
        }
      }
    }
  } else {
#pragma unroll
    for(int i=0;i<4;i++){
#pragma unroll
      for(int j=0;j<4;j++){
        const int n = nBase + wCol + j*16 + r16;
        const float bv = bias[n];
        const int col = nLoc + wCol + j*16 + r16;
#pragma unroll
        for(int reg=0;reg<4;reg++){
          const int mm = mBase + wRow + i*16 + quad*4 + reg;
          C[(size_t)mm*D + col] = f2bf(acc[i][j][reg] + bv);
        }
      }
    }
  }
}

// ---------------- merged proj-2: block-diagonal stacked GEMM ----------------
// A = stacked (3, Mrows, 1024) bf16; weight slice chosen by blockIdx.y>>5.
// C = stacked (3, Mrows, 1024) bf16. Grid (8, 96).
__global__ __launch_bounds__(256) void gemm_stack3(
    const u16* __restrict__ A, const u16* __restrict__ Bw,
    u16* __restrict__ C){
  __shared__ __align__(16) u16 As[128*32];
  __shared__ __align__(16) u16 Bs[128*32];
  const int wsel = blockIdx.y >> 5;
  const u16* B = Bw + (size_t)wsel*D*D;
  const int tid  = threadIdx.x;
  const int lane = tid & 63, wv = tid >> 6;
  const int wRow = (wv >> 1) * 64, wCol = (wv & 1) * 64;
  const int mBase = blockIdx.y*128, nBase = blockIdx.x*128;
  const int quad = lane >> 4, r16 = lane & 15;
  const int sRow = lane >> 2;
  const int sCol = (lane & 3) * 8;
  const char* smemA = (const char*)As;
  const char* smemB = (const char*)Bs;

  f32x4 acc[4][4];
#pragma unroll
  for(int i=0;i<4;i++)
#pragma unroll
    for(int j=0;j<4;j++) acc[i][j] = (f32x4)(0.f);

  for(int k0=0;k0<D;k0+=32){
#pragma unroll
    for(int rdn=0;rdn<2;rdn++){
      const int row = rdn*64 + wv*16 + sRow;
      gl2lds16(A + (size_t)(mBase + row)*D + k0 + sCol,
               (void*)((char*)As + rdn*4096 + wv*1024));
      gl2lds16(B + (size_t)(nBase + row)*D + k0 + sCol,
               (void*)((char*)Bs + rdn*4096 + wv*1024));
    }
    __syncthreads();
    bf16x8 af[4], bfr[4];
#pragma unroll
    for(int i=0;i<4;i++)
      af[i]  = *(const bf16x8*)(smemA + (wRow + i*16 + r16)*64 + quad*16);
#pragma unroll
    for(int j=0;j<4;j++)
      bfr[j] = *(const bf16x8*)(smemB + (wCol + j*16 + r16)*64 + quad*16);
#pragma unroll
    for(int i=0;i<4;i++)
#pragma unroll
      for(int j=0;j<4;j++)
        acc[i][j] = __builtin_amdgcn_mfma_f32_16x16x32_bf16(af[i], bfr[j], acc[i][j], 0,0,0);
    __syncthreads();
  }

#pragma unroll
  for(int i=0;i<4;i++){
#pragma unroll
    for(int j=0;j<4;j++){
      const int n = nBase + wCol + j*16 + r16;
#pragma unroll
      for(int reg=0;reg<4;reg++){
        const int mm = mBase + wRow + i*16 + quad*4 + reg;
        C[(size_t)mm*D + n] = f2bf(acc[i][j][reg]);
      }
    }
  }
}

// ---------------- out projection: fp32 + bias + residual --------------------
__global__ __launch_bounds__(256) void gemm_out(
    const u16* __restrict__ A, const u16* __restrict__ B, float* __restrict__ C,
    const float* __restrict__ bias, const float* __restrict__ resid){
  __shared__ __align__(16) u16 As[128*32];
  __shared__ __align__(16) u16 Bs[128*32];
  const int tid  = threadIdx.x;
  const int lane = tid & 63, wv = tid >> 6;
  const int wRow = (wv >> 1) * 64, wCol = (wv & 1) * 64;
  const int mBase = blockIdx.y*128, nBase = blockIdx.x*128;
  const int quad = lane >> 4, r16 = lane & 15;
  const int sRow = lane >> 2;
  const int sCol = (lane & 3) * 8;
  const char* smemA = (const char*)As;
  const char* smemB = (const char*)Bs;

  f32x4 acc[4][4];
#pragma unroll
  for(int i=0;i<4;i++)
#pragma unroll
    for(int j=0;j<4;j++) acc[i][j] = (f32x4)(0.f);

  for(int k0=0;k0<D;k0+=32){
#pragma unroll
    for(int rdn=0;rdn<2;rdn++){
      const int row = rdn*64 + wv*16 + sRow;
      gl2lds16(A + (size_t)(mBase + row)*D + k0 + sCol,
               (void*)((char*)As + rdn*4096 + wv*1024));
      gl2lds16(B + (size_t)(nBase + row)*D + k0 + sCol,
               (void*)((char*)Bs + rdn*4096 + wv*1024));
    }
    __syncthreads();
    bf16x8 af[4], bfr[4];
#pragma unroll
    for(int i=0;i<4;i++)
      af[i]  = *(const bf16x8*)(smemA + (wRow + i*16 + r16)*64 + quad*16);
#pragma unroll
    for(int j=0;j<4;j++)
      bfr[j] = *(const bf16x8*)(smemB + (wCol + j*16 + r16)*64 + quad*16);
#pragma unroll
    for(int i=0;i<4;i++)
#pragma unroll
      for(int j=0;j<4;j++)
        acc[i][j] = __builtin_amdgcn_mfma_f32_16x16x32_bf16(af[i], bfr[j], acc[i][j], 0,0,0);
    __syncthreads();
  }

#pragma unroll
  for(int i=0;i<4;i++){
#pragma unroll
    for(int j=0;j<4;j++){
      const int n = nBase + wCol + j*16 + r16;
      const float bv = bias[n];
#pragma unroll
      for(int reg=0;reg<4;reg++){
        const int mm = mBase + wRow + i*16 + quad*4 + reg;
        C[(size_t)mm*D + n] = acc[i][j][reg] + bv + resid[(size_t)mm*D + n];
      }
    }
  }
}

// ---------------- transpose V: (B,T,D) bf16 -> (BH,64,T) bf16 ---------------
__global__ __launch_bounds__(256) void transpose_v(const u16* __restrict__ v2,
                                                   u16* __restrict__ Vt){
  __shared__ u16 tile[64][65];
  const int bt = blockIdx.x;        // t tile
  const int bh = blockIdx.y;
  const int b = bh >> 4, h = bh & 15;
  const int tid = threadIdx.x;
  const int t0 = bt*64;
#pragma unroll
  for(int rep=0;rep<4;rep++){
    const int tl = rep*16 + (tid>>4);
    const int dl = (tid&15)*4;
    const ushort4 val = *(const ushort4*)(v2 + (size_t)((size_t)b*Tq + t0 + tl)*D + h*64 + dl);
    tile[tl][dl+0]=val.x; tile[tl][dl+1]=val.y; tile[tl][dl+2]=val.z; tile[tl][dl+3]=val.w;
  }
  __syncthreads();
#pragma unroll
  for(int rep=0;rep<4;rep++){
    const int dl = rep*16 + (tid>>4);
    const int tl = (tid&15)*4;
    ushort4 o;
    o.x=tile[tl+0][dl]; o.y=tile[tl+1][dl]; o.z=tile[tl+2][dl]; o.w=tile[tl+3][dl];
    *(ushort4*)(Vt + ((size_t)bh*64 + dl)*Tq + t0 + tl) = o;
  }
}

// ---------------- fused attention: scores + softmax + PV --------------------
// Per block: one 128-row q tile of one (b,h). Two-pass flash:
//   pass 1: S = 0.125 * Q K^T tile-by-tile -> online row max m, row sum l
//   pass 2: recompute S, P = exp(S-m)/l, write P (fp32, full causal half)
//           to attnW, and accumulate O = P V via an LDS P round-trip.
// attnW columns right of the causal range are zero-filled up front.
// 4 waves; wave w owns q rows [w*32, w*32+32). MFMA 16x16x32 bf16.
__global__ __launch_bounds__(256, 2) void attn_fused(
    const u16* __restrict__ q2, const u16* __restrict__ k2,
    const u16* __restrict__ Vt, float* __restrict__ attnW,
    u16* __restrict__ O){
  constexpr int PSS = 40;                       // P-stage row stride (u16)
  __shared__ __align__(16) u16 Ks[2*128*32];    // [kk][128 rows][32 k] 16KB
  __shared__ __align__(16) u16 Vs[4*64*32];     // [chunk][64 d][32 t]  16KB
  __shared__ __align__(16) u16 QPs[2*128*32];   // Q tiles; reused as P stage

  // XCD-aware decode: linear id n -> (tRow, bh); all 16 tRow-blocks of a
  // 4-head group land on one XCD so K/V/Q slices stay L2-resident.
  // Load-balance: all 512 blocks are co-resident (2/CU) and the dispatcher
  // pairs block n with n+256 on one CU. tRow work scales with (tRow+1), so
  // complement tRow in the second round: pair work (t+1)+(16-t)=17 tiles,
  // zero-fill (15-t)+t=15 tiles -- constant per CU.
  const int n    = blockIdx.x + 16*blockIdx.y;  // 0..511
  const int t0c  = (n >> 3) & 15;
  const int tRow = ((n >> 8) & 1) ? (15 - t0c) : t0c;
  const int bh   = (n & 7) + 8*(n >> 7);
  const int b = bh >> 4, h = bh & 15;
  const int tid = threadIdx.x, lane = tid & 63, w = tid >> 6;
  const int quad = lane >> 4, r16 = lane & 15;
  const u16* Qg = q2 + ((size_t)b*Tq + (size_t)tRow*128)*D + h*64;
  const u16* Kg = k2 + ((size_t)b*Tq)*D + h*64;
  const u16* Vg = Vt + (size_t)bh*64*Tq;
  float* Wg = attnW + (size_t)bh*Tq*Tq + (size_t)tRow*128*Tq;

  // 1) zero non-causal columns (fire-and-forget; drains during pass 1)
  for(int ct2 = tRow+1; ct2 < Tq/128; ++ct2){
#pragma unroll
    for(int it=0; it<16; ++it){
      const int r = it*8 + (tid>>5);
      ((f32x4*)(Wg + (size_t)r*Tq + ct2*128))[tid & 31] = (f32x4)(0.f);
    }
  }

  // 2) stage Q once -> registers
#pragma unroll
  for(int rep=0; rep<4; ++rep){
    const int kb = rep*4 + w;
    const int kk = kb >> 3, row = (kb&7)*16 + (lane>>2);
    gl2lds16(Qg + (size_t)row*D + kk*32 + (lane&3)*8,
             (void*)((char*)QPs + kb*1024));
  }
  __syncthreads();
  bf16x8 af[2][2];
#pragma unroll
  for(int i=0;i<2;i++)
#pragma unroll
    for(int kk=0;kk<2;kk++)
      af[i][kk] = *(const bf16x8*)((const char*)QPs + kk*8192
                    + (w*32 + i*16 + r16)*64 + quad*16);

  float m[2][4], l[2][4];
#pragma unroll
  for(int i=0;i<2;i++)
#pragma unroll
    for(int rg=0;rg<4;rg++){ m[i][rg] = -1e30f; l[i][rg] = 0.f; }

  // -------- pass 1: stats --------
  for(int ct=0; ct<=tRow; ++ct){
#pragma unroll
    for(int rep=0; rep<4; ++rep){
      const int kb = rep*4 + w;
      const int kk = kb >> 3, row = (kb&7)*16 + (lane>>2);
      gl2lds16(Kg + ((size_t)ct*128 + row)*D + kk*32 + (lane&3)*8,
               (void*)((char*)Ks + kb*1024));
    }
    __syncthreads();
    f32x4 acc[2][8];
#pragma unroll
    for(int i=0;i<2;i++)
#pragma unroll
      for(int j=0;j<8;j++) acc[i][j] = (f32x4)(0.f);
#pragma unroll
    for(int kk=0;kk<2;kk++){
#pragma unroll
      for(int j=0;j<8;j++){
        const bf16x8 bfj = *(const bf16x8*)((const char*)Ks + kk*8192
                             + (j*16 + r16)*64 + quad*16);
#pragma unroll
        for(int i=0;i<2;i++)
          acc[i][j] = __builtin_amdgcn_mfma_f32_16x16x32_bf16(af[i][kk], bfj, acc[i][j],0,0,0);
      }
    }
    const bool diag = (ct == tRow);
#pragma unroll
    for(int i=0;i<2;i++){
#pragma unroll
      for(int rg=0; rg<4; ++rg){
        const int rowg = w*32 + i*16 + quad*4 + rg;
        float sv[8]; float mx = -1e30f;
#pragma unroll
        for(int j=0;j<8;j++){
          float s = acc[i][j][rg]*0.125f;
          if(diag && (j*16 + r16) > rowg) s = -1e30f;
          sv[j]=s; mx = fmaxf(mx,s);
        }
#pragma unroll
        for(int o=8;o;o>>=1) mx = fmaxf(mx, __shfl_xor(mx,o));
        const float mn = fmaxf(m[i][rg], mx);
        float ls = 0.f;
#pragma unroll
        for(int j=0;j<8;j++) ls += __expf(sv[j]-mn);
#pragma unroll
        for(int o=8;o;o>>=1) ls += __shfl_xor(ls,o);
        l[i][rg] = l[i][rg]*__expf(m[i][rg]-mn) + ls;
        m[i][rg] = mn;
      }
    }
    __syncthreads();
  }

  float rinv[2][4];
#pragma unroll
  for(int i=0;i<2;i++)
#pragma unroll
    for(int rg=0;rg<4;rg++) rinv[i][rg] = 1.0f / l[i][rg];
  f32x4 oacc[2][4];
#pragma unroll
  for(int i=0;i<2;i++)
#pragma unroll
    for(int j=0;j<4;j++) oacc[i][j] = (f32x4)(0.f);

  char* psb = (char*)QPs + w*(32*PSS*2);        // per-wave P stage

  // -------- pass 2: write P + accumulate O --------
  for(int ct=0; ct<=tRow; ++ct){
#pragma unroll
    for(int rep=0; rep<4; ++rep){
      const int kb = rep*4 + w;
      const int kk = kb >> 3, row = (kb&7)*16 + (lane>>2);
      gl2lds16(Kg + ((size_t)ct*128 + row)*D + kk*32 + (lane&3)*8,
               (void*)((char*)Ks + kb*1024));
      const int vrow = w*16 + (lane>>2);
      gl2lds16(Vg + (size_t)vrow*Tq + ct*128 + rep*32 + (lane&3)*8,
               (void*)((char*)Vs + (rep*4 + w)*1024));
    }
    __syncthreads();
    f32x4 acc[2][8];
#pragma unroll
    for(int i=0;i<2;i++)
#pragma unroll
      for(int j=0;j<8;j++) acc[i][j] = (f32x4)(0.f);
#pragma unroll
    for(int kk=0;kk<2;kk++){
#pragma unroll
      for(int j=0;j<8;j++){
        const bf16x8 bfj = *(const bf16x8*)((const char*)Ks + kk*8192
                             + (j*16 + r16)*64 + quad*16);
#pragma unroll
        for(int i=0;i<2;i++)
          acc[i][j] = __builtin_amdgcn_mfma_f32_16x16x32_bf16(af[i][kk], bfj, acc[i][j],0,0,0);
      }
    }
    const bool diag = (ct == tRow);
#pragma unroll
    for(int c=0;c<4;c++){                        // 32-k chunk of this tile
#pragma unroll
      for(int i=0;i<2;i++){
#pragma unroll
        for(int jj=0;jj<2;jj++){
          const int j = c*2 + jj;
#pragma unroll
          for(int rg=0;rg<4;rg++){
            const int rowl = i*16 + quad*4 + rg;
            const int rowg = w*32 + rowl;
            float s = acc[i][j][rg]*0.125f;
            if(diag && (j*16 + r16) > rowg) s = -1e30f;
            const float p = __expf(s - m[i][rg]) * rinv[i][rg];
            Wg[(size_t)rowg*Tq + ct*128 + j*16 + r16] = p;
            *(u16*)(psb + rowl*(PSS*2) + (jj*16 + r16)*2) = f2bf(p);
          }
        }
      }
      asm volatile("s_waitcnt lgkmcnt(0)" ::: "memory");
      __builtin_amdgcn_sched_barrier(0);
      bf16x8 pa[2];
#pragma unroll
      for(int i=0;i<2;i++)
        pa[i] = *(const bf16x8*)(psb + (i*16 + r16)*(PSS*2) + quad*16);
#pragma unroll
      for(int j2=0;j2<4;j2++){
        const bf16x8 bv = *(const bf16x8*)((const char*)Vs + c*4096
                            + (j2*16 + r16)*64 + quad*16);
        oacc[0][j2] = __builtin_amdgcn_mfma_f32_16x16x32_bf16(pa[0], bv, oacc[0][j2],0,0,0);
        oacc[1][j2] = __builtin_amdgcn_mfma_f32_16x16x32_bf16(pa[1], bv, oacc[1][j2],0,0,0);
      }
      asm volatile("s_waitcnt lgkmcnt(0)" ::: "memory");   // pa reads done
      __builtin_amdgcn_sched_barrier(0);                   // before overwrite
    }
    __syncthreads();
  }

  // O (bf16, (B,T,D) layout)
#pragma unroll
  for(int i=0;i<2;i++)
#pragma unroll
    for(int j2=0;j2<4;j2++)
#pragma unroll
      for(int rg=0;rg<4;rg++){
        const int trow = tRow*128 + w*32 + i*16 + quad*4 + rg;
        O[((size_t)b*Tq + trow)*D + h*64 + j2*16 + r16] = f2bf(oacc[i][j2][rg]);
      }
}

extern "C" void kernel_launch(void* const* d_in, const int* in_sizes, int n_in,
                              void* d_out, int out_size, void* d_ws, size_t ws_size,
                              hipStream_t stream){
  const float* x    = (const float*)d_in[0];
  const float* Win  = (const float*)d_in[1];   // (3072,1024)
  const float* bin  = (const float*)d_in[2];   // (3072)
  const float* Wout = (const float*)d_in[3];   // (1024,1024)
  const float* bout = (const float*)d_in[4];   // (1024)
  const float* gam  = (const float*)d_in[5];
  const float* bet  = (const float*)d_in[6];

  float* out   = (float*)d_out;
  float* attnW = out + (size_t)Mrows*D;        // (B,H,T,T) fp32

  // ws layout (bytes), 64 MB total:
  //  0.. 6 MB : Winb (bf16 3072x1024)
  //  6.. 8 MB : Woutb
  //  8..16 MB : xn  -> reused as Vt (xn dead after proj-1)
  // 16..40 MB : qkv1 stacked (3,M,1024) -> first 8 MB reused as O after proj-2
  // 40..64 MB : qkv2 stacked (3,M,1024); rope table overlaps its head
  //             (table dead before proj-2 writes qkv2)
  const size_t MB = 1u<<20;
  char* ws = (char*)d_ws;
  u16* Winb  = (u16*)(ws + 0);
  u16* Woutb = (u16*)(ws + 6*MB);
  u16* xn    = (u16*)(ws + 8*MB);
  u16* Vt    = xn;
  u16* qkv1  = (u16*)(ws + 16*MB);
  u16* Oat   = qkv1;
  u16* qkv2  = (u16*)(ws + 40*MB);
  float2* tab = (float2*)(ws + 40*MB);

  const size_t DD = (size_t)D*D;
  const u16* q2 = qkv2;
  const u16* k2 = qkv2 + (size_t)Mrows*D;
  const u16* v2 = qkv2 + 2*(size_t)Mrows*D;

  // 0) weight conversion fp32 -> bf16, rotary table
  cvt_kernel<<<(3*DD/4)/256, 256, 0, stream>>>(Win, Winb);
  cvt_kernel<<<(DD/4)/256, 256, 0, stream>>>(Wout, Woutb);
  rope_tab_kernel<<<(Tq*32)/256, 256, 0, stream>>>(tab);

  // 1) LayerNorm -> bf16
  ln_kernel<<<Mrows, 256, 0, stream>>>(x, gam, bet, xn);

  // 2) merged first projection (+bias) with fused RoPE -> qkv1 stacked
  gemm_qkv1<<<dim3(3*D/128, Mrows/128), 256, 0, stream>>>(xn, Winb, bin, tab, qkv1);

  // 3) merged second projection (block-diagonal, no bias) -> qkv2 stacked
  gemm_stack3<<<dim3(D/128, 3*Mrows/128), 256, 0, stream>>>(qkv1, Winb, qkv2);

  // 4) transpose V -> (BH,64,T)
  transpose_v<<<dim3(Tq/64, Bc*NHc), 256, 0, stream>>>(v2, Vt);

  // 5) fused scores + softmax + PV: writes attnW (fp32, incl. zero upper
  //    triangle) once and O (bf16) directly.
  attn_fused<<<dim3(Tq/128, Bc*NHc), 256, 0, stream>>>(q2, k2, Vt, attnW, Oat);

  // 6) out projection + bias + residual (fp32 out)
  gemm_out<<<dim3(D/128, Mrows/128), 256, 0, stream>>>(Oat, Woutb, out, bout, x);
}

// Round 4
// 797.155 us; speedup vs baseline: 1.0019x; 1.0019x over previous
//
#include <hip/hip_runtime.h>
#include <math.h>
#include <stdint.h>

typedef unsigned short u16;
typedef __bf16 bf16x8 __attribute__((ext_vector_type(8)));
typedef float f32x4 __attribute__((ext_vector_type(4)));

constexpr int Tq = 2048;
constexpr int D  = 1024;
constexpr int NHc = 16;
constexpr int Bc = 2;
constexpr int Mrows = Bc * Tq;   // 4096

__device__ __forceinline__ float wsum(float v){
#pragma unroll
  for(int o=32;o;o>>=1) v += __shfl_xor(v,o);
  return v;
}
__device__ __forceinline__ u16 f2bf(float f){          // RNE fp32->bf16
  union{ float f; unsigned u; } v; v.f = f;
  unsigned r = v.u + 0x7fffu + ((v.u >> 16) & 1u);
  return (u16)(r >> 16);
}
__device__ __forceinline__ float bf2f(u16 b){
  union{ unsigned u; float f; } v; v.u = ((unsigned)b) << 16;
  return v.f;
}
__device__ __forceinline__ void gl2lds16(const void* g, void* l){
  // async global->LDS, 16B/lane; LDS dst = wave-uniform base + lane*16
  __builtin_amdgcn_global_load_lds(
      (const __attribute__((address_space(1))) unsigned int*)g,
      (__attribute__((address_space(3))) unsigned int*)l, 16, 0, 0);
}

// ---------------- prep: weight cvt (Win, Wout) + rope table + LayerNorm -----
// region-dispatched single launch:
//   blocks [0,3072)      : cvt Win   (float4/thread)
//   blocks [3072,4096)   : cvt Wout
//   blocks [4096,4352)   : rope cos/sin table (T x 32 float2)
//   blocks [4352,8448)   : LayerNorm row = bid-4352 -> bf16
__global__ __launch_bounds__(256) void prep_kernel(
    const float* __restrict__ Win,  u16* __restrict__ Winb,
    const float* __restrict__ Wout, u16* __restrict__ Woutb,
    float2* __restrict__ tab,
    const float* __restrict__ x, const float* __restrict__ g,
    const float* __restrict__ b, u16* __restrict__ xn){
  const int bid = blockIdx.x;
  const int tid = threadIdx.x;
  if(bid < 4096){
    const float* s = (bid < 3072) ? Win  : Wout;
    u16*         d = (bid < 3072) ? Winb : Woutb;
    const int i = (bid < 3072 ? bid : bid-3072)*256 + tid;
    const float4 v = ((const float4*)s)[i];
    ushort4 o; o.x=f2bf(v.x); o.y=f2bf(v.y); o.z=f2bf(v.z); o.w=f2bf(v.w);
    ((ushort4*)d)[i] = o;
    return;
  }
  if(bid < 4352){
    const int idx = (bid-4096)*256 + tid;   // T*32 = 65536
    const int t = idx >> 5, fi = idx & 31;
    const float inv = powf(10000.0f, -(float)fi*(1.0f/32.0f));
    const float ang = (float)t * inv;
    tab[idx] = make_float2(cosf(ang), sinf(ang));
    return;
  }
  const int row = bid - 4352;
  const float4 v = ((const float4*)(x + (size_t)row*D))[tid];
  float s = v.x+v.y+v.z+v.w;
  float q = v.x*v.x+v.y*v.y+v.z*v.z+v.w*v.w;
  s = wsum(s); q = wsum(q);
  __shared__ float sb[4], qb[4];
  if((tid&63)==0){ sb[tid>>6]=s; qb[tid>>6]=q; }
  __syncthreads();
  const float ts = sb[0]+sb[1]+sb[2]+sb[3];
  const float tq = qb[0]+qb[1]+qb[2]+qb[3];
  const float mu   = ts*(1.0f/D);
  const float var  = tq*(1.0f/D) - mu*mu;
  const float rstd = rsqrtf(var + 1e-5f);
  const float4 gv = ((const float4*)g)[tid];
  const float4 bv = ((const float4*)b)[tid];
  ushort4 o;
  o.x = f2bf((v.x-mu)*rstd*gv.x + bv.x);
  o.y = f2bf((v.y-mu)*rstd*gv.y + bv.y);
  o.z = f2bf((v.z-mu)*rstd*gv.z + bv.z);
  o.w = f2bf((v.w-mu)*rstd*gv.w + bv.w);
  ((ushort4*)(xn + (size_t)row*D))[tid] = o;
}

// ---------------- merged proj-1: [q|k|v] = xn @ Win^T + bin, RoPE fused -----
// A (M,1024) bf16, B (3072,1024) bf16. Grid (24, 32). Output stacked
// (3, Mrows, 1024) bf16; for q/k slices the rotary rotation is applied
// in-register on the fp32 accumulators (pair (hp, hp+32) = (j, j+2)).
__global__ __launch_bounds__(256) void gemm_qkv1(
    const u16* __restrict__ A, const u16* __restrict__ B,
    const float* __restrict__ bias, const float2* __restrict__ tab,
    u16* __restrict__ out){
  __shared__ __align__(16) u16 As[128*32];
  __shared__ __align__(16) u16 Bs[128*32];
  const int tid  = threadIdx.x;
  const int lane = tid & 63, wv = tid >> 6;
  const int wRow = (wv >> 1) * 64, wCol = (wv & 1) * 64;
  const int mBase = blockIdx.y*128, nBase = blockIdx.x*128;
  const int quad = lane >> 4, r16 = lane & 15;
  const int sRow = lane >> 2;
  const int sCol = (lane & 3) * 8;
  const char* smemA = (const char*)As;
  const char* smemB = (const char*)Bs;

  f32x4 acc[4][4];
#pragma unroll
  for(int i=0;i<4;i++)
#pragma unroll
    for(int j=0;j<4;j++) acc[i][j] = (f32x4)(0.f);

  for(int k0=0;k0<D;k0+=32){
#pragma unroll
    for(int rdn=0;rdn<2;rdn++){
      const int row = rdn*64 + wv*16 + sRow;
      gl2lds16(A + (size_t)(mBase + row)*D + k0 + sCol,
               (void*)((char*)As + rdn*4096 + wv*1024));
      gl2lds16(B + (size_t)(nBase + row)*D + k0 + sCol,
               (void*)((char*)Bs + rdn*4096 + wv*1024));
    }
    __syncthreads();
    bf16x8 af[4], bfr[4];
#pragma unroll
    for(int i=0;i<4;i++)
      af[i]  = *(const bf16x8*)(smemA + (wRow + i*16 + r16)*64 + quad*16);
#pragma unroll
    for(int j=0;j<4;j++)
      bfr[j] = *(const bf16x8*)(smemB + (wCol + j*16 + r16)*64 + quad*16);
#pragma unroll
    for(int i=0;i<4;i++)
#pragma unroll
      for(int j=0;j<4;j++)
        acc[i][j] = __builtin_amdgcn_mfma_f32_16x16x32_bf16(af[i], bfr[j], acc[i][j], 0,0,0);
    __syncthreads();
  }

  const int sel  = nBase >> 10;          // 0=q 1=k 2=v (tiles never straddle)
  const int nLoc = nBase & 1023;
  u16* C = out + (size_t)sel*Mrows*D;
  if(sel < 2){
#pragma unroll
    for(int i=0;i<4;i++){
#pragma unroll
      for(int jp=0;jp<2;jp++){
        const int hp  = jp*16 + r16;           // 0..31 within head
        const int col = nLoc + wCol + hp;
        const float bv0 = bias[nBase + wCol + hp];
        const float bv1 = bias[nBase + wCol + hp + 32];
#pragma unroll
        for(int reg=0;reg<4;reg++){
          const int mm = mBase + wRow + i*16 + quad*4 + reg;
          const float2 cs = tab[((mm & (Tq-1))<<5) + hp];
          const float a0 = acc[i][jp][reg]   + bv0;
          const float a1 = acc[i][jp+2][reg] + bv1;
          C[(size_t)mm*D + col]      = f2bf(a0*cs.x - a1*cs.y);
          C[(size_t)mm*D + col + 32] = f2bf(a1*cs.x + a0*cs.y);
        }
      }
    }
  } else {
#pragma unroll
    for(int i=0;i<4;i++){
#pragma unroll
      for(int j=0;j<4;j++){
        const int n = nBase + wCol + j*16 + r16;
        const float bv = bias[n];
        const int col = nLoc + wCol + j*16 + r16;
#pragma unroll
        for(int reg=0;reg<4;reg++){
          const int mm = mBase + wRow + i*16 + quad*4 + reg;
          C[(size_t)mm*D + col] = f2bf(acc[i][j][reg] + bv);
        }
      }
    }
  }
}

// ---------------- merged proj-2: block-diagonal stacked GEMM ----------------
// A = stacked (3, Mrows, 1024) bf16; weight slice chosen by blockIdx.y>>5.
// q/k slices -> qkv2 row-major. v slice -> written DIRECTLY into Vt
// (BH,64,T) transposed layout (4 acc regs = 4 consecutive t -> ushort4).
// Grid (8, 96).
__global__ __launch_bounds__(256) void gemm_stack3(
    const u16* __restrict__ A, const u16* __restrict__ Bw,
    u16* __restrict__ C, u16* __restrict__ Vt){
  __shared__ __align__(16) u16 As[128*32];
  __shared__ __align__(16) u16 Bs[128*32];
  const int wsel = blockIdx.y >> 5;
  const u16* B = Bw + (size_t)wsel*D*D;
  const int tid  = threadIdx.x;
  const int lane = tid & 63, wv = tid >> 6;
  const int wRow = (wv >> 1) * 64, wCol = (wv & 1) * 64;
  const int mBase = blockIdx.y*128, nBase = blockIdx.x*128;
  const int quad = lane >> 4, r16 = lane & 15;
  const int sRow = lane >> 2;
  const int sCol = (lane & 3) * 8;
  const char* smemA = (const char*)As;
  const char* smemB = (const char*)Bs;

  f32x4 acc[4][4];
#pragma unroll
  for(int i=0;i<4;i++)
#pragma unroll
    for(int j=0;j<4;j++) acc[i][j] = (f32x4)(0.f);

  for(int k0=0;k0<D;k0+=32){
#pragma unroll
    for(int rdn=0;rdn<2;rdn++){
      const int row = rdn*64 + wv*16 + sRow;
      gl2lds16(A + (size_t)(mBase + row)*D + k0 + sCol,
               (void*)((char*)As + rdn*4096 + wv*1024));
      gl2lds16(B + (size_t)(nBase + row)*D + k0 + sCol,
               (void*)((char*)Bs + rdn*4096 + wv*1024));
    }
    __syncthreads();
    bf16x8 af[4], bfr[4];
#pragma unroll
    for(int i=0;i<4;i++)
      af[i]  = *(const bf16x8*)(smemA + (wRow + i*16 + r16)*64 + quad*16);
#pragma unroll
    for(int j=0;j<4;j++)
      bfr[j] = *(const bf16x8*)(smemB + (wCol + j*16 + r16)*64 + quad*16);
#pragma unroll
    for(int i=0;i<4;i++)
#pragma unroll
      for(int j=0;j<4;j++)
        acc[i][j] = __builtin_amdgcn_mfma_f32_16x16x32_bf16(af[i], bfr[j], acc[i][j], 0,0,0);
    __syncthreads();
  }

  if(wsel < 2){
#pragma unroll
    for(int i=0;i<4;i++){
#pragma unroll
      for(int j=0;j<4;j++){
        const int n = nBase + wCol + j*16 + r16;
#pragma unroll
        for(int reg=0;reg<4;reg++){
          const int mm = mBase + wRow + i*16 + quad*4 + reg;
          C[(size_t)mm*D + n] = f2bf(acc[i][j][reg]);
        }
      }
    }
  } else {
    // v slice: write transposed into Vt (BH,64,T)
#pragma unroll
    for(int i=0;i<4;i++){
#pragma unroll
      for(int j=0;j<4;j++){
        const int n = nBase + wCol + j*16 + r16;   // 0..1023
        const int h = n >> 6, dloc = n & 63;
        const int mv = (mBase - 64*128) + wRow + i*16 + quad*4;  // v-row
        const int b = mv >> 11, t = mv & (Tq-1);
        ushort4 o;
        o.x = f2bf(acc[i][j][0]); o.y = f2bf(acc[i][j][1]);
        o.z = f2bf(acc[i][j][2]); o.w = f2bf(acc[i][j][3]);
        *(ushort4*)(Vt + ((size_t)(b*16+h)*64 + dloc)*Tq + t) = o;
      }
    }
  }
}

// ---------------- out projection: fp32 + bias + residual --------------------
__global__ __launch_bounds__(256) void gemm_out(
    const u16* __restrict__ A, const u16* __restrict__ B, float* __restrict__ C,
    const float* __restrict__ bias, const float* __restrict__ resid){
  __shared__ __align__(16) u16 As[128*32];
  __shared__ __align__(16) u16 Bs[128*32];
  const int tid  = threadIdx.x;
  const int lane = tid & 63, wv = tid >> 6;
  const int wRow = (wv >> 1) * 64, wCol = (wv & 1) * 64;
  const int mBase = blockIdx.y*128, nBase = blockIdx.x*128;
  const int quad = lane >> 4, r16 = lane & 15;
  const int sRow = lane >> 2;
  const int sCol = (lane & 3) * 8;
  const char* smemA = (const char*)As;
  const char* smemB = (const char*)Bs;

  f32x4 acc[4][4];
#pragma unroll
  for(int i=0;i<4;i++)
#pragma unroll
    for(int j=0;j<4;j++) acc[i][j] = (f32x4)(0.f);

  for(int k0=0;k0<D;k0+=32){
#pragma unroll
    for(int rdn=0;rdn<2;rdn++){
      const int row = rdn*64 + wv*16 + sRow;
      gl2lds16(A + (size_t)(mBase + row)*D + k0 + sCol,
               (void*)((char*)As + rdn*4096 + wv*1024));
      gl2lds16(B + (size_t)(nBase + row)*D + k0 + sCol,
               (void*)((char*)Bs + rdn*4096 + wv*1024));
    }
    __syncthreads();
    bf16x8 af[4], bfr[4];
#pragma unroll
    for(int i=0;i<4;i++)
      af[i]  = *(const bf16x8*)(smemA + (wRow + i*16 + r16)*64 + quad*16);
#pragma unroll
    for(int j=0;j<4;j++)
      bfr[j] = *(const bf16x8*)(smemB + (wCol + j*16 + r16)*64 + quad*16);
#pragma unroll
    for(int i=0;i<4;i++)
#pragma unroll
      for(int j=0;j<4;j++)
        acc[i][j] = __builtin_amdgcn_mfma_f32_16x16x32_bf16(af[i], bfr[j], acc[i][j], 0,0,0);
    __syncthreads();
  }

#pragma unroll
  for(int i=0;i<4;i++){
#pragma unroll
    for(int j=0;j<4;j++){
      const int n = nBase + wCol + j*16 + r16;
      const float bv = bias[n];
#pragma unroll
      for(int reg=0;reg<4;reg++){
        const int mm = mBase + wRow + i*16 + quad*4 + reg;
        C[(size_t)mm*D + n] = acc[i][j][reg] + bv + resid[(size_t)mm*D + n];
      }
    }
  }
}

// ---------------- fused attention: scores + softmax + PV --------------------
// Per block: one 128-row q tile of one (b,h). Two-pass flash:
//   pass 1: S = 0.125 * Q K^T tile-by-tile -> online row max m, row sum l
//   pass 2: recompute S, P = exp(S-m)/l, write P (fp32, full causal half)
//           to attnW, and accumulate O = P V via an LDS P round-trip.
// attnW columns right of the causal range are zero-filled up front.
// 4 waves; wave w owns q rows [w*32, w*32+32). MFMA 16x16x32 bf16.
__global__ __launch_bounds__(256, 2) void attn_fused(
    const u16* __restrict__ q2, const u16* __restrict__ k2,
    const u16* __restrict__ Vt, float* __restrict__ attnW,
    u16* __restrict__ O){
  constexpr int PSS = 40;                       // P-stage row stride (u16)
  __shared__ __align__(16) u16 Ks[2*128*32];    // [kk][128 rows][32 k] 16KB
  __shared__ __align__(16) u16 Vs[4*64*32];     // [chunk][64 d][32 t]  16KB
  __shared__ __align__(16) u16 QPs[2*128*32];   // Q tiles; reused as P stage

  // XCD-aware decode: linear id n -> (tRow, bh); all 16 tRow-blocks of a
  // 4-head group land on one XCD so K/V/Q slices stay L2-resident.
  // tRow complement in the second dispatch round (kept from R2; neutral
  // but harmless -- kernel is write-drain-bound, uniform 1 MB/block).
  const int n    = blockIdx.x + 16*blockIdx.y;  // 0..511
  const int t0c  = (n >> 3) & 15;
  const int tRow = ((n >> 8) & 1) ? (15 - t0c) : t0c;
  const int bh   = (n & 7) + 8*(n >> 7);
  const int b = bh >> 4, h = bh & 15;
  const int tid = threadIdx.x, lane = tid & 63, w = tid >> 6;
  const int quad = lane >> 4, r16 = lane & 15;
  const u16* Qg = q2 + ((size_t)b*Tq + (size_t)tRow*128)*D + h*64;
  const u16* Kg = k2 + ((size_t)b*Tq)*D + h*64;
  const u16* Vg = Vt + (size_t)bh*64*Tq;
  float* Wg = attnW + (size_t)bh*Tq*Tq + (size_t)tRow*128*Tq;

  // 1) zero non-causal columns (fire-and-forget; drains during pass 1)
  for(int ct2 = tRow+1; ct2 < Tq/128; ++ct2){
#pragma unroll
    for(int it=0; it<16; ++it){
      const int r = it*8 + (tid>>5);
      ((f32x4*)(Wg + (size_t)r*Tq + ct2*128))[tid & 31] = (f32x4)(0.f);
    }
  }

  // 2) stage Q once -> registers
#pragma unroll
  for(int rep=0; rep<4; ++rep){
    const int kb = rep*4 + w;
    const int kk = kb >> 3, row = (kb&7)*16 + (lane>>2);
    gl2lds16(Qg + (size_t)row*D + kk*32 + (lane&3)*8,
             (void*)((char*)QPs + kb*1024));
  }
  __syncthreads();
  bf16x8 af[2][2];
#pragma unroll
  for(int i=0;i<2;i++)
#pragma unroll
    for(int kk=0;kk<2;kk++)
      af[i][kk] = *(const bf16x8*)((const char*)QPs + kk*8192
                    + (w*32 + i*16 + r16)*64 + quad*16);

  float m[2][4], l[2][4];
#pragma unroll
  for(int i=0;i<2;i++)
#pragma unroll
    for(int rg=0;rg<4;rg++){ m[i][rg] = -1e30f; l[i][rg] = 0.f; }

  // -------- pass 1: stats --------
  for(int ct=0; ct<=tRow; ++ct){
#pragma unroll
    for(int rep=0; rep<4; ++rep){
      const int kb = rep*4 + w;
      const int kk = kb >> 3, row = (kb&7)*16 + (lane>>2);
      gl2lds16(Kg + ((size_t)ct*128 + row)*D + kk*32 + (lane&3)*8,
               (void*)((char*)Ks + kb*1024));
    }
    __syncthreads();
    f32x4 acc[2][8];
#pragma unroll
    for(int i=0;i<2;i++)
#pragma unroll
      for(int j=0;j<8;j++) acc[i][j] = (f32x4)(0.f);
#pragma unroll
    for(int kk=0;kk<2;kk++){
#pragma unroll
      for(int j=0;j<8;j++){
        const bf16x8 bfj = *(const bf16x8*)((const char*)Ks + kk*8192
                             + (j*16 + r16)*64 + quad*16);
#pragma unroll
        for(int i=0;i<2;i++)
          acc[i][j] = __builtin_amdgcn_mfma_f32_16x16x32_bf16(af[i][kk], bfj, acc[i][j],0,0,0);
      }
    }
    const bool diag = (ct == tRow);
#pragma unroll
    for(int i=0;i<2;i++){
#pragma unroll
      for(int rg=0; rg<4; ++rg){
        const int rowg = w*32 + i*16 + quad*4 + rg;
        float sv[8]; float mx = -1e30f;
#pragma unroll
        for(int j=0;j<8;j++){
          float s = acc[i][j][rg]*0.125f;
          if(diag && (j*16 + r16) > rowg) s = -1e30f;
          sv[j]=s; mx = fmaxf(mx,s);
        }
#pragma unroll
        for(int o=8;o;o>>=1) mx = fmaxf(mx, __shfl_xor(mx,o));
        const float mn = fmaxf(m[i][rg], mx);
        float ls = 0.f;
#pragma unroll
        for(int j=0;j<8;j++) ls += __expf(sv[j]-mn);
#pragma unroll
        for(int o=8;o;o>>=1) ls += __shfl_xor(ls,o);
        l[i][rg] = l[i][rg]*__expf(m[i][rg]-mn) + ls;
        m[i][rg] = mn;
      }
    }
    __syncthreads();
  }

  float rinv[2][4];
#pragma unroll
  for(int i=0;i<2;i++)
#pragma unroll
    for(int rg=0;rg<4;rg++) rinv[i][rg] = 1.0f / l[i][rg];
  f32x4 oacc[2][4];
#pragma unroll
  for(int i=0;i<2;i++)
#pragma unroll
    for(int j=0;j<4;j++) oacc[i][j] = (f32x4)(0.f);

  char* psb = (char*)QPs + w*(32*PSS*2);        // per-wave P stage

  // -------- pass 2: write P + accumulate O --------
  for(int ct=0; ct<=tRow; ++ct){
#pragma unroll
    for(int rep=0; rep<4; ++rep){
      const int kb = rep*4 + w;
      const int kk = kb >> 3, row = (kb&7)*16 + (lane>>2);
      gl2lds16(Kg + ((size_t)ct*128 + row)*D + kk*32 + (lane&3)*8,
               (void*)((char*)Ks + kb*1024));
      const int vrow = w*16 + (lane>>2);
      gl2lds16(Vg + (size_t)vrow*Tq + ct*128 + rep*32 + (lane&3)*8,
               (void*)((char*)Vs + (rep*4 + w)*1024));
    }
    __syncthreads();
    f32x4 acc[2][8];
#pragma unroll
    for(int i=0;i<2;i++)
#pragma unroll
      for(int j=0;j<8;j++) acc[i][j] = (f32x4)(0.f);
#pragma unroll
    for(int kk=0;kk<2;kk++){
#pragma unroll
      for(int j=0;j<8;j++){
        const bf16x8 bfj = *(const bf16x8*)((const char*)Ks + kk*8192
                             + (j*16 + r16)*64 + quad*16);
#pragma unroll
        for(int i=0;i<2;i++)
          acc[i][j] = __builtin_amdgcn_mfma_f32_16x16x32_bf16(af[i][kk], bfj, acc[i][j],0,0,0);
      }
    }
    const bool diag = (ct == tRow);
#pragma unroll
    for(int c=0;c<4;c++){                        // 32-k chunk of this tile
#pragma unroll
      for(int i=0;i<2;i++){
#pragma unroll
        for(int jj=0;jj<2;jj++){
          const int j = c*2 + jj;
#pragma unroll
          for(int rg=0;rg<4;rg++){
            const int rowl = i*16 + quad*4 + rg;
            const int rowg = w*32 + rowl;
            float s = acc[i][j][rg]*0.125f;
            if(diag && (j*16 + r16) > rowg) s = -1e30f;
            const float p = __expf(s - m[i][rg]) * rinv[i][rg];
            Wg[(size_t)rowg*Tq + ct*128 + j*16 + r16] = p;
            *(u16*)(psb + rowl*(PSS*2) + (jj*16 + r16)*2) = f2bf(p);
          }
        }
      }
      asm volatile("s_waitcnt lgkmcnt(0)" ::: "memory");
      __builtin_amdgcn_sched_barrier(0);
      bf16x8 pa[2];
#pragma unroll
      for(int i=0;i<2;i++)
        pa[i] = *(const bf16x8*)(psb + (i*16 + r16)*(PSS*2) + quad*16);
#pragma unroll
      for(int j2=0;j2<4;j2++){
        const bf16x8 bv = *(const bf16x8*)((const char*)Vs + c*4096
                            + (j2*16 + r16)*64 + quad*16);
        oacc[0][j2] = __builtin_amdgcn_mfma_f32_16x16x32_bf16(pa[0], bv, oacc[0][j2],0,0,0);
        oacc[1][j2] = __builtin_amdgcn_mfma_f32_16x16x32_bf16(pa[1], bv, oacc[1][j2],0,0,0);
      }
      asm volatile("s_waitcnt lgkmcnt(0)" ::: "memory");   // pa reads done
      __builtin_amdgcn_sched_barrier(0);                   // before overwrite
    }
    __syncthreads();
  }

  // O (bf16, (B,T,D) layout)
#pragma unroll
  for(int i=0;i<2;i++)
#pragma unroll
    for(int j2=0;j2<4;j2++)
#pragma unroll
      for(int rg=0;rg<4;rg++){
        const int trow = tRow*128 + w*32 + i*16 + quad*4 + rg;
        O[((size_t)b*Tq + trow)*D + h*64 + j2*16 + r16] = f2bf(oacc[i][j2][rg]);
      }
}

extern "C" void kernel_launch(void* const* d_in, const int* in_sizes, int n_in,
                              void* d_out, int out_size, void* d_ws, size_t ws_size,
                              hipStream_t stream){
  const float* x    = (const float*)d_in[0];
  const float* Win  = (const float*)d_in[1];   // (3072,1024)
  const float* bin  = (const float*)d_in[2];   // (3072)
  const float* Wout = (const float*)d_in[3];   // (1024,1024)
  const float* bout = (const float*)d_in[4];   // (1024)
  const float* gam  = (const float*)d_in[5];
  const float* bet  = (const float*)d_in[6];

  float* out   = (float*)d_out;
  float* attnW = out + (size_t)Mrows*D;        // (B,H,T,T) fp32

  // ws layout (bytes), 64 MB total:
  //  0.. 6 MB : Winb (bf16 3072x1024)
  //  6.. 8 MB : Woutb
  //  8..16 MB : xn  -> reused as Vt (xn dead after proj-1; Vt written by
  //             gemm_stack3's v-slice epilogue)
  // 16..40 MB : qkv1 stacked (3,M,1024) -> first 8 MB reused as O after proj-2
  // 40..56 MB : qkv2 q,k slices; rope table overlaps its head
  //             (table dead before proj-2 writes qkv2)
  const size_t MB = 1u<<20;
  char* ws = (char*)d_ws;
  u16* Winb  = (u16*)(ws + 0);
  u16* Woutb = (u16*)(ws + 6*MB);
  u16* xn    = (u16*)(ws + 8*MB);
  u16* Vt    = xn;
  u16* qkv1  = (u16*)(ws + 16*MB);
  u16* Oat   = qkv1;
  u16* qkv2  = (u16*)(ws + 40*MB);
  float2* tab = (float2*)(ws + 40*MB);

  const u16* q2 = qkv2;
  const u16* k2 = qkv2 + (size_t)Mrows*D;

  // 0) prep: weight cvt + rope table + LayerNorm (single launch)
  prep_kernel<<<8448, 256, 0, stream>>>(Win, Winb, Wout, Woutb, tab,
                                        x, gam, bet, xn);

  // 1) merged first projection (+bias) with fused RoPE -> qkv1 stacked
  gemm_qkv1<<<dim3(3*D/128, Mrows/128), 256, 0, stream>>>(xn, Winb, bin, tab, qkv1);

  // 2) merged second projection (block-diagonal, no bias) -> qkv2 (q,k)
  //    and Vt (v, transposed epilogue)
  gemm_stack3<<<dim3(D/128, 3*Mrows/128), 256, 0, stream>>>(qkv1, Winb, qkv2, Vt);

  // 3) fused scores + softmax + PV: writes attnW (fp32, incl. zero upper
  //    triangle) once and O (bf16) directly.
  attn_fused<<<dim3(Tq/128, Bc*NHc), 256, 0, stream>>>(q2, k2, Vt, attnW, Oat);

  // 4) out projection + bias + residual (fp32 out)
  gemm_out<<<dim3(D/128, Mrows/128), 256, 0, stream>>>(Oat, Woutb, out, bout, x);
}

// Round 5
// 763.582 us; speedup vs baseline: 1.0459x; 1.0440x over previous
//
#include <hip/hip_runtime.h>
#include <math.h>
#include <stdint.h>

typedef unsigned short u16;
typedef __bf16 bf16x8 __attribute__((ext_vector_type(8)));
typedef float f32x4 __attribute__((ext_vector_type(4)));

constexpr int Tq = 2048;
constexpr int D  = 1024;
constexpr int NHc = 16;
constexpr int Bc = 2;
constexpr int Mrows = Bc * Tq;   // 4096

__device__ __forceinline__ float wsum(float v){
#pragma unroll
  for(int o=32;o;o>>=1) v += __shfl_xor(v,o);
  return v;
}
__device__ __forceinline__ u16 f2bf(float f){          // RNE fp32->bf16
  union{ float f; unsigned u; } v; v.f = f;
  unsigned r = v.u + 0x7fffu + ((v.u >> 16) & 1u);
  return (u16)(r >> 16);
}
__device__ __forceinline__ float bf2f(u16 b){
  union{ unsigned u; float f; } v; v.u = ((unsigned)b) << 16;
  return v.f;
}
__device__ __forceinline__ void gl2lds16(const void* g, void* l){
  // async global->LDS, 16B/lane; LDS dst = wave-uniform base + lane*16
  __builtin_amdgcn_global_load_lds(
      (const __attribute__((address_space(1))) unsigned int*)g,
      (__attribute__((address_space(3))) unsigned int*)l, 16, 0, 0);
}

// ---------------- prep: weight cvt (Win, Wout) + rope table + LayerNorm -----
__global__ __launch_bounds__(256) void prep_kernel(
    const float* __restrict__ Win,  u16* __restrict__ Winb,
    const float* __restrict__ Wout, u16* __restrict__ Woutb,
    float2* __restrict__ tab,
    const float* __restrict__ x, const float* __restrict__ g,
    const float* __restrict__ b, u16* __restrict__ xn){
  const int bid = blockIdx.x;
  const int tid = threadIdx.x;
  if(bid < 4096){
    const float* s = (bid < 3072) ? Win  : Wout;
    u16*         d = (bid < 3072) ? Winb : Woutb;
    const int i = (bid < 3072 ? bid : bid-3072)*256 + tid;
    const float4 v = ((const float4*)s)[i];
    ushort4 o; o.x=f2bf(v.x); o.y=f2bf(v.y); o.z=f2bf(v.z); o.w=f2bf(v.w);
    ((ushort4*)d)[i] = o;
    return;
  }
  if(bid < 4352){
    const int idx = (bid-4096)*256 + tid;   // T*32 = 65536
    const int t = idx >> 5, fi = idx & 31;
    const float inv = powf(10000.0f, -(float)fi*(1.0f/32.0f));
    const float ang = (float)t * inv;
    tab[idx] = make_float2(cosf(ang), sinf(ang));
    return;
  }
  const int row = bid - 4352;
  const float4 v = ((const float4*)(x + (size_t)row*D))[tid];
  float s = v.x+v.y+v.z+v.w;
  float q = v.x*v.x+v.y*v.y+v.z*v.z+v.w*v.w;
  s = wsum(s); q = wsum(q);
  __shared__ float sb[4], qb[4];
  if((tid&63)==0){ sb[tid>>6]=s; qb[tid>>6]=q; }
  __syncthreads();
  const float ts = sb[0]+sb[1]+sb[2]+sb[3];
  const float tq = qb[0]+qb[1]+qb[2]+qb[3];
  const float mu   = ts*(1.0f/D);
  const float var  = tq*(1.0f/D) - mu*mu;
  const float rstd = rsqrtf(var + 1e-5f);
  const float4 gv = ((const float4*)g)[tid];
  const float4 bv = ((const float4*)b)[tid];
  ushort4 o;
  o.x = f2bf((v.x-mu)*rstd*gv.x + bv.x);
  o.y = f2bf((v.y-mu)*rstd*gv.y + bv.y);
  o.z = f2bf((v.z-mu)*rstd*gv.z + bv.z);
  o.w = f2bf((v.w-mu)*rstd*gv.w + bv.w);
  ((ushort4*)(xn + (size_t)row*D))[tid] = o;
}

// ---------------- merged proj-1: [q|k|v] = xn @ Win^T + bin, RoPE fused -----
__global__ __launch_bounds__(256) void gemm_qkv1(
    const u16* __restrict__ A, const u16* __restrict__ B,
    const float* __restrict__ bias, const float2* __restrict__ tab,
    u16* __restrict__ out){
  __shared__ __align__(16) u16 As[128*32];
  __shared__ __align__(16) u16 Bs[128*32];
  const int tid  = threadIdx.x;
  const int lane = tid & 63, wv = tid >> 6;
  const int wRow = (wv >> 1) * 64, wCol = (wv & 1) * 64;
  const int mBase = blockIdx.y*128, nBase = blockIdx.x*128;
  const int quad = lane >> 4, r16 = lane & 15;
  const int sRow = lane >> 2;
  const int sCol = (lane & 3) * 8;
  const char* smemA = (const char*)As;
  const char* smemB = (const char*)Bs;

  f32x4 acc[4][4];
#pragma unroll
  for(int i=0;i<4;i++)
#pragma unroll
    for(int j=0;j<4;j++) acc[i][j] = (f32x4)(0.f);

  for(int k0=0;k0<D;k0+=32){
#pragma unroll
    for(int rdn=0;rdn<2;rdn++){
      const int row = rdn*64 + wv*16 + sRow;
      gl2lds16(A + (size_t)(mBase + row)*D + k0 + sCol,
               (void*)((char*)As + rdn*4096 + wv*1024));
      gl2lds16(B + (size_t)(nBase + row)*D + k0 + sCol,
               (void*)((char*)Bs + rdn*4096 + wv*1024));
    }
    __syncthreads();
    bf16x8 af[4], bfr[4];
#pragma unroll
    for(int i=0;i<4;i++)
      af[i]  = *(const bf16x8*)(smemA + (wRow + i*16 + r16)*64 + quad*16);
#pragma unroll
    for(int j=0;j<4;j++)
      bfr[j] = *(const bf16x8*)(smemB + (wCol + j*16 + r16)*64 + quad*16);
#pragma unroll
    for(int i=0;i<4;i++)
#pragma unroll
      for(int j=0;j<4;j++)
        acc[i][j] = __builtin_amdgcn_mfma_f32_16x16x32_bf16(af[i], bfr[j], acc[i][j], 0,0,0);
    __syncthreads();
  }

  const int sel  = nBase >> 10;          // 0=q 1=k 2=v (tiles never straddle)
  const int nLoc = nBase & 1023;
  u16* C = out + (size_t)sel*Mrows*D;
  if(sel < 2){
#pragma unroll
    for(int i=0;i<4;i++){
#pragma unroll
      for(int jp=0;jp<2;jp++){
        const int hp  = jp*16 + r16;           // 0..31 within head
        const int col = nLoc + wCol + hp;
        const float bv0 = bias[nBase + wCol + hp];
        const float bv1 = bias[nBase + wCol + hp + 32];
#pragma unroll
        for(int reg=0;reg<4;reg++){
          const int mm = mBase + wRow + i*16 + quad*4 + reg;
          const float2 cs = tab[((mm & (Tq-1))<<5) + hp];
          const float a0 = acc[i][jp][reg]   + bv0;
          const float a1 = acc[i][jp+2][reg] + bv1;
          C[(size_t)mm*D + col]      = f2bf(a0*cs.x - a1*cs.y);
          C[(size_t)mm*D + col + 32] = f2bf(a1*cs.x + a0*cs.y);
        }
      }
    }
  } else {
#pragma unroll
    for(int i=0;i<4;i++){
#pragma unroll
      for(int j=0;j<4;j++){
        const int n = nBase + wCol + j*16 + r16;
        const float bv = bias[n];
        const int col = nLoc + wCol + j*16 + r16;
#pragma unroll
        for(int reg=0;reg<4;reg++){
          const int mm = mBase + wRow + i*16 + quad*4 + reg;
          C[(size_t)mm*D + col] = f2bf(acc[i][j][reg] + bv);
        }
      }
    }
  }
}

// ---------------- merged proj-2: block-diagonal stacked GEMM ----------------
// A = stacked (3, Mrows, 1024) bf16; weight slice chosen by blockIdx.y>>5.
// q/k slices -> qkv2 row-major. v slice -> Vt (BH,64,T) via per-wave LDS
// transpose (coalesced 64B segments). Grid (8, 96).
__global__ __launch_bounds__(256) void gemm_stack3(
    const u16* __restrict__ A, const u16* __restrict__ Bw,
    u16* __restrict__ C, u16* __restrict__ Vt){
  __shared__ __align__(16) u16 As[128*32];
  __shared__ __align__(16) u16 Bs[128*32];
  const int wsel = blockIdx.y >> 5;
  const u16* B = Bw + (size_t)wsel*D*D;
  const int tid  = threadIdx.x;
  const int lane = tid & 63, wv = tid >> 6;
  const int wRow = (wv >> 1) * 64, wCol = (wv & 1) * 64;
  const int mBase = blockIdx.y*128, nBase = blockIdx.x*128;
  const int quad = lane >> 4, r16 = lane & 15;
  const int sRow = lane >> 2;
  const int sCol = (lane & 3) * 8;
  const char* smemA = (const char*)As;
  const char* smemB = (const char*)Bs;

  f32x4 acc[4][4];
#pragma unroll
  for(int i=0;i<4;i++)
#pragma unroll
    for(int j=0;j<4;j++) acc[i][j] = (f32x4)(0.f);

  for(int k0=0;k0<D;k0+=32){
#pragma unroll
    for(int rdn=0;rdn<2;rdn++){
      const int row = rdn*64 + wv*16 + sRow;
      gl2lds16(A + (size_t)(mBase + row)*D + k0 + sCol,
               (void*)((char*)As + rdn*4096 + wv*1024));
      gl2lds16(B + (size_t)(nBase + row)*D + k0 + sCol,
               (void*)((char*)Bs + rdn*4096 + wv*1024));
    }
    __syncthreads();
    bf16x8 af[4], bfr[4];
#pragma unroll
    for(int i=0;i<4;i++)
      af[i]  = *(const bf16x8*)(smemA + (wRow + i*16 + r16)*64 + quad*16);
#pragma unroll
    for(int j=0;j<4;j++)
      bfr[j] = *(const bf16x8*)(smemB + (wCol + j*16 + r16)*64 + quad*16);
#pragma unroll
    for(int i=0;i<4;i++)
#pragma unroll
      for(int j=0;j<4;j++)
        acc[i][j] = __builtin_amdgcn_mfma_f32_16x16x32_bf16(af[i], bfr[j], acc[i][j], 0,0,0);
    __syncthreads();
  }

  if(wsel < 2){
#pragma unroll
    for(int i=0;i<4;i++){
#pragma unroll
      for(int j=0;j<4;j++){
        const int n = nBase + wCol + j*16 + r16;
#pragma unroll
        for(int reg=0;reg<4;reg++){
          const int mm = mBase + wRow + i*16 + quad*4 + reg;
          C[(size_t)mm*D + n] = f2bf(acc[i][j][reg]);
        }
      }
    }
  } else {
    // v slice: per-wave LDS transpose (4KB slice), then coalesced 64B stores
    // into Vt (BH,64,T). After the K-loop's final sync, As/Bs are free.
    u16* tbuf = (wv < 2) ? (As + wv*2048) : (Bs + (wv-2)*2048);  // 2048 u16
    const int mv0 = (mBase - 64*128) + wRow;       // wave's first v-row
#pragma unroll
    for(int hi=0; hi<2; ++hi){
      // write phase: rows [hi*32, hi*32+32) -> tbuf[n][m] (64 x 32 u16)
#pragma unroll
      for(int ii=0; ii<2; ++ii){
        const int i = hi*2 + ii;
        const int ml = ii*16 + quad*4;
#pragma unroll
        for(int j=0;j<4;j++){
          const int nl = j*16 + r16;
          ushort4 o;
          o.x = f2bf(acc[i][j][0]); o.y = f2bf(acc[i][j][1]);
          o.z = f2bf(acc[i][j][2]); o.w = f2bf(acc[i][j][3]);
          *(ushort4*)(tbuf + nl*32 + ml) = o;
        }
      }
      asm volatile("s_waitcnt lgkmcnt(0)" ::: "memory");
      __builtin_amdgcn_sched_barrier(0);
      // read phase: 8 lanes cover 32 consecutive t per n-row, 8 rows/instr
#pragma unroll
      for(int rr=0; rr<8; ++rr){
        const int nl  = rr*8 + (lane>>3);
        const int msg = (lane&7)*4;
        const ushort4 o = *(const ushort4*)(tbuf + nl*32 + msg);
        const int nn = nBase + wCol + nl;
        const int hh = nn >> 6, dloc = nn & 63;
        const int mv = mv0 + hi*32 + msg;
        const int bb = mv >> 11, t = mv & (Tq-1);
        *(ushort4*)(Vt + ((size_t)(bb*16+hh)*64 + dloc)*Tq + t) = o;
      }
      asm volatile("s_waitcnt lgkmcnt(0)" ::: "memory");
      __builtin_amdgcn_sched_barrier(0);
    }
  }
}

// ---------------- out projection: fp32 + bias + residual --------------------
__global__ __launch_bounds__(256) void gemm_out(
    const u16* __restrict__ A, const u16* __restrict__ B, float* __restrict__ C,
    const float* __restrict__ bias, const float* __restrict__ resid){
  __shared__ __align__(16) u16 As[128*32];
  __shared__ __align__(16) u16 Bs[128*32];
  const int tid  = threadIdx.x;
  const int lane = tid & 63, wv = tid >> 6;
  const int wRow = (wv >> 1) * 64, wCol = (wv & 1) * 64;
  const int mBase = blockIdx.y*128, nBase = blockIdx.x*128;
  const int quad = lane >> 4, r16 = lane & 15;
  const int sRow = lane >> 2;
  const int sCol = (lane & 3) * 8;
  const char* smemA = (const char*)As;
  const char* smemB = (const char*)Bs;

  f32x4 acc[4][4];
#pragma unroll
  for(int i=0;i<4;i++)
#pragma unroll
    for(int j=0;j<4;j++) acc[i][j] = (f32x4)(0.f);

  for(int k0=0;k0<D;k0+=32){
#pragma unroll
    for(int rdn=0;rdn<2;rdn++){
      const int row = rdn*64 + wv*16 + sRow;
      gl2lds16(A + (size_t)(mBase + row)*D + k0 + sCol,
               (void*)((char*)As + rdn*4096 + wv*1024));
      gl2lds16(B + (size_t)(nBase + row)*D + k0 + sCol,
               (void*)((char*)Bs + rdn*4096 + wv*1024));
    }
    __syncthreads();
    bf16x8 af[4], bfr[4];
#pragma unroll
    for(int i=0;i<4;i++)
      af[i]  = *(const bf16x8*)(smemA + (wRow + i*16 + r16)*64 + quad*16);
#pragma unroll
    for(int j=0;j<4;j++)
      bfr[j] = *(const bf16x8*)(smemB + (wCol + j*16 + r16)*64 + quad*16);
#pragma unroll
    for(int i=0;i<4;i++)
#pragma unroll
      for(int j=0;j<4;j++)
        acc[i][j] = __builtin_amdgcn_mfma_f32_16x16x32_bf16(af[i], bfr[j], acc[i][j], 0,0,0);
    __syncthreads();
  }

#pragma unroll
  for(int i=0;i<4;i++){
#pragma unroll
    for(int j=0;j<4;j++){
      const int n = nBase + wCol + j*16 + r16;
      const float bv = bias[n];
#pragma unroll
      for(int reg=0;reg<4;reg++){
        const int mm = mBase + wRow + i*16 + quad*4 + reg;
        C[(size_t)mm*D + n] = acc[i][j][reg] + bv + resid[(size_t)mm*D + n];
      }
    }
  }
}

// ---------------- fused attention: scores + softmax + PV --------------------
// 8 waves x 512 threads; wave w owns q rows [w*16, w*16+16). Two-pass flash:
//   pass 1: S = 0.125 * Q K^T -> PER-LANE running (m,l), reduced once at end
//   pass 2: recompute S, P = exp(S-m)/l, write P (fp32) to attnW and
//           accumulate O = P V via per-wave LDS P round-trip.
__global__ __launch_bounds__(512, 4) void attn_fused(
    const u16* __restrict__ q2, const u16* __restrict__ k2,
    const u16* __restrict__ Vt, float* __restrict__ attnW,
    u16* __restrict__ O){
  constexpr int PSS = 40;                       // P-stage row stride (u16)
  __shared__ __align__(16) u16 Ks[2*128*32];    // [kk][128 rows][32 k] 16KB
  __shared__ __align__(16) u16 Vs[4*64*32];     // [tchunk][64 d][32 t] 16KB
  __shared__ __align__(16) u16 QPs[2*128*32];   // Q tiles; reused as P stage

  const int n    = blockIdx.x + 16*blockIdx.y;  // 0..511
  const int t0c  = (n >> 3) & 15;
  const int tRow = ((n >> 8) & 1) ? (15 - t0c) : t0c;
  const int bh   = (n & 7) + 8*(n >> 7);
  const int b = bh >> 4, h = bh & 15;
  const int tid = threadIdx.x, lane = tid & 63, w = tid >> 6;   // w in [0,8)
  const int quad = lane >> 4, r16 = lane & 15;
  const u16* Qg = q2 + ((size_t)b*Tq + (size_t)tRow*128)*D + h*64;
  const u16* Kg = k2 + ((size_t)b*Tq)*D + h*64;
  const u16* Vg = Vt + (size_t)bh*64*Tq;
  float* Wg = attnW + (size_t)bh*Tq*Tq + (size_t)tRow*128*Tq;

  // 1) zero non-causal columns (fire-and-forget; drains during pass 1)
  for(int ct2 = tRow+1; ct2 < Tq/128; ++ct2){
#pragma unroll
    for(int it=0; it<8; ++it){
      const int r = it*16 + (tid>>5);
      ((f32x4*)(Wg + (size_t)r*Tq + ct2*128))[tid & 31] = (f32x4)(0.f);
    }
  }

  // 2) stage Q once -> registers (16 x 1KB chunks, 8 waves x 2 reps)
#pragma unroll
  for(int rep=0; rep<2; ++rep){
    const int kb = rep*8 + w;
    const int kk = kb >> 3, row = (kb&7)*16 + (lane>>2);
    gl2lds16(Qg + (size_t)row*D + kk*32 + (lane&3)*8,
             (void*)((char*)QPs + kb*1024));
  }
  __syncthreads();
  bf16x8 af[2];
#pragma unroll
  for(int kk=0;kk<2;kk++)
    af[kk] = *(const bf16x8*)((const char*)QPs + kk*8192
                  + (w*16 + r16)*64 + quad*16);

  float m[4], l[4];
#pragma unroll
  for(int rg=0;rg<4;rg++){ m[rg] = -1e30f; l[rg] = 0.f; }

  // -------- pass 1: per-lane online stats --------
  for(int ct=0; ct<=tRow; ++ct){
#pragma unroll
    for(int rep=0; rep<2; ++rep){
      const int kb = rep*8 + w;
      const int kk = kb >> 3, row = (kb&7)*16 + (lane>>2);
      gl2lds16(Kg + ((size_t)ct*128 + row)*D + kk*32 + (lane&3)*8,
               (void*)((char*)Ks + kb*1024));
    }
    __syncthreads();
    f32x4 acc[8];
#pragma unroll
    for(int j=0;j<8;j++) acc[j] = (f32x4)(0.f);
#pragma unroll
    for(int kk=0;kk<2;kk++){
#pragma unroll
      for(int j=0;j<8;j++){
        const bf16x8 bfj = *(const bf16x8*)((const char*)Ks + kk*8192
                             + (j*16 + r16)*64 + quad*16);
        acc[j] = __builtin_amdgcn_mfma_f32_16x16x32_bf16(af[kk], bfj, acc[j],0,0,0);
      }
    }
    const bool diag = (ct == tRow);
#pragma unroll
    for(int rg=0; rg<4; ++rg){
      const int rowg = w*16 + quad*4 + rg;
      float mx = m[rg];
      float sv[8];
#pragma unroll
      for(int j=0;j<8;j++){
        float s = acc[j][rg]*0.125f;
        if(diag && (j*16 + r16) > rowg) s = -1e30f;
        sv[j]=s; mx = fmaxf(mx,s);
      }
      float ls = l[rg]*__expf(m[rg]-mx);
#pragma unroll
      for(int j=0;j<8;j++) ls += __expf(sv[j]-mx);
      m[rg]=mx; l[rg]=ls;
    }
    __syncthreads();
  }

  // reduce per-lane stats across the 16 lanes of each row (once)
  float rinv[4];
#pragma unroll
  for(int rg=0;rg<4;rg++){
    float mfin = m[rg];
#pragma unroll
    for(int o=8;o;o>>=1) mfin = fmaxf(mfin, __shfl_xor(mfin,o));
    float lf = l[rg]*__expf(m[rg]-mfin);
#pragma unroll
    for(int o=8;o;o>>=1) lf += __shfl_xor(lf,o);
    m[rg] = mfin; rinv[rg] = 1.0f/lf;
  }
  f32x4 oacc[4];
#pragma unroll
  for(int j=0;j<4;j++) oacc[j] = (f32x4)(0.f);

  char* psb = (char*)QPs + w*(16*PSS*2);        // per-wave P stage (1.25KB)

  // -------- pass 2: write P + accumulate O --------
  for(int ct=0; ct<=tRow; ++ct){
#pragma unroll
    for(int rep=0; rep<2; ++rep){
      const int kb = rep*8 + w;
      const int kk = kb >> 3, row = (kb&7)*16 + (lane>>2);
      gl2lds16(Kg + ((size_t)ct*128 + row)*D + kk*32 + (lane&3)*8,
               (void*)((char*)Ks + kb*1024));
      const int tch = kb & 3, dgrp = kb >> 2;
      gl2lds16(Vg + (size_t)(dgrp*16 + (lane>>2))*Tq + ct*128 + tch*32 + (lane&3)*8,
               (void*)((char*)Vs + (tch*4 + dgrp)*1024));
    }
    __syncthreads();
    f32x4 acc[8];
#pragma unroll
    for(int j=0;j<8;j++) acc[j] = (f32x4)(0.f);
#pragma unroll
    for(int kk=0;kk<2;kk++){
#pragma unroll
      for(int j=0;j<8;j++){
        const bf16x8 bfj = *(const bf16x8*)((const char*)Ks + kk*8192
                             + (j*16 + r16)*64 + quad*16);
        acc[j] = __builtin_amdgcn_mfma_f32_16x16x32_bf16(af[kk], bfj, acc[j],0,0,0);
      }
    }
    const bool diag = (ct == tRow);
#pragma unroll
    for(int c=0;c<4;c++){                        // 32-k chunk of this tile
#pragma unroll
      for(int jj=0;jj<2;jj++){
        const int j = c*2 + jj;
#pragma unroll
        for(int rg=0;rg<4;rg++){
          const int rowl = quad*4 + rg;
          const int rowg = w*16 + rowl;
          float s = acc[j][rg]*0.125f;
          if(diag && (j*16 + r16) > rowg) s = -1e30f;
          const float p = __expf(s - m[rg]) * rinv[rg];
          Wg[(size_t)rowg*Tq + ct*128 + j*16 + r16] = p;
          *(u16*)(psb + rowl*(PSS*2) + (jj*16 + r16)*2) = f2bf(p);
        }
      }
      asm volatile("s_waitcnt lgkmcnt(0)" ::: "memory");
      __builtin_amdgcn_sched_barrier(0);
      const bf16x8 pa = *(const bf16x8*)(psb + r16*(PSS*2) + quad*16);
#pragma unroll
      for(int j2=0;j2<4;j2++){
        const bf16x8 bv = *(const bf16x8*)((const char*)Vs + c*4096
                            + (j2*16 + r16)*64 + quad*16);
        oacc[j2] = __builtin_amdgcn_mfma_f32_16x16x32_bf16(pa, bv, oacc[j2],0,0,0);
      }
      asm volatile("s_waitcnt lgkmcnt(0)" ::: "memory");   // pa reads done
      __builtin_amdgcn_sched_barrier(0);                   // before overwrite
    }
    __syncthreads();
  }

  // O (bf16, (B,T,D) layout)
#pragma unroll
  for(int j2=0;j2<4;j2++)
#pragma unroll
    for(int rg=0;rg<4;rg++){
      const int trow = tRow*128 + w*16 + quad*4 + rg;
      O[((size_t)b*Tq + trow)*D + h*64 + j2*16 + r16] = f2bf(oacc[j2][rg]);
    }
}

extern "C" void kernel_launch(void* const* d_in, const int* in_sizes, int n_in,
                              void* d_out, int out_size, void* d_ws, size_t ws_size,
                              hipStream_t stream){
  const float* x    = (const float*)d_in[0];
  const float* Win  = (const float*)d_in[1];   // (3072,1024)
  const float* bin  = (const float*)d_in[2];   // (3072)
  const float* Wout = (const float*)d_in[3];   // (1024,1024)
  const float* bout = (const float*)d_in[4];   // (1024)
  const float* gam  = (const float*)d_in[5];
  const float* bet  = (const float*)d_in[6];

  float* out   = (float*)d_out;
  float* attnW = out + (size_t)Mrows*D;        // (B,H,T,T) fp32

  // ws layout: see R3 notes (unchanged)
  const size_t MB = 1u<<20;
  char* ws = (char*)d_ws;
  u16* Winb  = (u16*)(ws + 0);
  u16* Woutb = (u16*)(ws + 6*MB);
  u16* xn    = (u16*)(ws + 8*MB);
  u16* Vt    = xn;
  u16* qkv1  = (u16*)(ws + 16*MB);
  u16* Oat   = qkv1;
  u16* qkv2  = (u16*)(ws + 40*MB);
  float2* tab = (float2*)(ws + 40*MB);

  const u16* q2 = qkv2;
  const u16* k2 = qkv2 + (size_t)Mrows*D;

  // 0) prep: weight cvt + rope table + LayerNorm (single launch)
  prep_kernel<<<8448, 256, 0, stream>>>(Win, Winb, Wout, Woutb, tab,
                                        x, gam, bet, xn);

  // 1) merged first projection (+bias) with fused RoPE -> qkv1 stacked
  gemm_qkv1<<<dim3(3*D/128, Mrows/128), 256, 0, stream>>>(xn, Winb, bin, tab, qkv1);

  // 2) merged second projection (block-diagonal, no bias) -> qkv2 (q,k)
  //    and Vt (v, LDS-transposed coalesced epilogue)
  gemm_stack3<<<dim3(D/128, 3*Mrows/128), 256, 0, stream>>>(qkv1, Winb, qkv2, Vt);

  // 3) fused scores + softmax + PV (8 waves): attnW (fp32) + O (bf16)
  attn_fused<<<dim3(Tq/128, Bc*NHc), 512, 0, stream>>>(q2, k2, Vt, attnW, Oat);

  // 4) out projection + bias + residual (fp32 out)
  gemm_out<<<dim3(D/128, Mrows/128), 256, 0, stream>>>(Oat, Woutb, out, bout, x);
}